// Round 19
// baseline (204.044 us; speedup 1.0000x reference)
//
#include <hip/hip_runtime.h>

#define VOCAB 128
#define EMB   8
#define HID   32
#define BATCH 512
#define SEQ   512
#define G4    128   // 4*HID
#define KB    8     // recurrence steps per phase

#define LOG2E 1.4426950408889634f

typedef float v2f __attribute__((ext_vector_type(2)));

// ---------------------------------------------------------------------------
// Kernel 1: proj[v][r] = (dot(emb[v], w_ih[r]) + b_ih[r] + b_hh[r]) * rowscale
// rowscale folds exp->exp2: g-rows [64,96): 2*log2e ; others: log2e
// ---------------------------------------------------------------------------
__global__ void build_proj(const float* __restrict__ emb,
                           const float* __restrict__ w_ih,
                           const float* __restrict__ b_ih,
                           const float* __restrict__ b_hh,
                           float* __restrict__ proj) {
    int idx = blockIdx.x * blockDim.x + threadIdx.x;   // 0 .. 16383
    int v = idx >> 7;
    int r = idx & 127;
    float acc = b_ih[r] + b_hh[r];
#pragma unroll
    for (int e = 0; e < EMB; ++e)
        acc += emb[v * EMB + e] * w_ih[r * EMB + e];
    float sc = (r >= 64 && r < 96) ? (2.0f * LOG2E) : LOG2E;
    proj[v * G4 + r] = acc * sc;
}

// ---------------------------------------------------------------------------
// Fast gate nonlinearities (inputs pre-scaled by log2e / 2*log2e). Proven R10.
// ---------------------------------------------------------------------------
__device__ __forceinline__ float sig2(float x) {
    return __builtin_amdgcn_rcpf(1.0f + __builtin_amdgcn_exp2f(-x));
}
__device__ __forceinline__ float tanh2(float x2) {
    return 1.0f - 2.0f * __builtin_amdgcn_rcpf(__builtin_amdgcn_exp2f(x2) + 1.0f);
}

// ---------------------------------------------------------------------------
// Alias-proof half-broadcast (proven R10).
// ---------------------------------------------------------------------------
__device__ __forceinline__ void half_bcast(float acc, float& lo, float& hi) {
    asm("v_mov_b32 %0, %2\n\t"
        "v_mov_b32 %1, %2\n\t"
        "v_permlane32_swap_b32 %0, %1"
        : "=&v"(lo), "=&v"(hi)
        : "v"(acc));
}

// ---------------------------------------------------------------------------
// Kernel 2: LSTM recurrence — R15 VERBATIM (133-134 us, green).
// ---------------------------------------------------------------------------
__global__ __launch_bounds__(64)
__attribute__((amdgpu_waves_per_eu(1, 1)))
void lstm_rec(
    const int*   __restrict__ tokens,   // [B][T]
    const float* __restrict__ w_hh,     // [128][32]
    const float* __restrict__ proj,     // [128][128], pre-scaled
    float*       __restrict__ h_out)    // [B*T][32]
{
    const int b    = blockIdx.x;
    const int lane = threadIdx.x;      // 0..63

    __shared__ float sproj[VOCAB * G4];   // 64 KB

    {
        const float4* src = (const float4*)proj;
        float4*       dst = (float4*)sproj;
#pragma unroll 4
        for (int i = 0; i < (VOCAB * G4 / 4) / 64; ++i)
            dst[i * 64 + lane] = src[i * 64 + lane];
    }

    const float sc1 = (lane < 32) ? (2.0f * LOG2E) : LOG2E;
    v2f w0p[HID / 2], w1p[HID / 2];
#pragma unroll
    for (int p = 0; p < HID / 2; ++p) {
        w0p[p][0] = w_hh[lane * HID + 2 * p]     * LOG2E;
        w0p[p][1] = w_hh[lane * HID + 2 * p + 1] * LOG2E;
        w1p[p][0] = w_hh[(lane + 64) * HID + 2 * p]     * sc1;
        w1p[p][1] = w_hh[(lane + 64) * HID + 2 * p + 1] * sc1;
    }
#pragma unroll
    for (int p = 0; p < HID / 2; ++p) {
        asm volatile("" : "+v"(w0p[p]), "+v"(w1p[p]));
    }

    const int* tok = tokens + b * SEQ;
    int tv[KB];
    {
        int4 a = ((const int4*)tok)[lane * 2];
        int4 d = ((const int4*)tok)[lane * 2 + 1];
        tv[0] = a.x; tv[1] = a.y; tv[2] = a.z; tv[3] = a.w;
        tv[4] = d.x; tv[5] = d.y; tv[6] = d.z; tv[7] = d.w;
    }

    __syncthreads();

    float h = 0.0f, c = 0.0f;
    float* hp = h_out + (size_t)b * SEQ * HID + lane;
    float hsave[KB];

    float xc0[KB], xc1[KB];
#pragma unroll
    for (int k = 0; k < KB; ++k) {
        int tk = __builtin_amdgcn_readlane(tv[k], 0);
        xc0[k] = sproj[tk * G4 + lane];
        xc1[k] = sproj[tk * G4 + 64 + lane];
    }

    for (int t0 = 0; t0 < SEQ; t0 += KB) {
        const int nb = t0 + KB;
        const int ln = (nb < SEQ) ? (nb >> 3) : 0;
        float xn0[KB], xn1[KB];
#pragma unroll
        for (int k = 0; k < KB; ++k) {
            int tk = __builtin_amdgcn_readlane(tv[k], ln);
            xn0[k] = sproj[tk * G4 + lane];
            xn1[k] = sproj[tk * G4 + 64 + lane];
        }
        __builtin_amdgcn_sched_barrier(0);

#pragma unroll
        for (int k = 0; k < KB; ++k) {
            unsigned hb = __float_as_uint(h);
            v2f hup[HID / 2];
#pragma unroll
            for (int p = 0; p < HID / 2; ++p) {
                hup[p][0] = __uint_as_float(__builtin_amdgcn_readlane(hb, 2 * p));
                hup[p][1] = __uint_as_float(__builtin_amdgcn_readlane(hb, 2 * p + 1));
            }
            __builtin_amdgcn_sched_barrier(0);

            v2f sA = {xc0[k], 0.0f}, sB = {0.0f, 0.0f},
                sC = {0.0f, 0.0f},   sD = {0.0f, 0.0f};
            v2f uA = {xc1[k], 0.0f}, uB = {0.0f, 0.0f},
                uC = {0.0f, 0.0f},   uD = {0.0f, 0.0f};
#pragma unroll
            for (int p = 0; p < HID / 2; p += 4) {
                sA = __builtin_elementwise_fma(hup[p],     w0p[p],     sA);
                sB = __builtin_elementwise_fma(hup[p + 1], w0p[p + 1], sB);
                sC = __builtin_elementwise_fma(hup[p + 2], w0p[p + 2], sC);
                sD = __builtin_elementwise_fma(hup[p + 3], w0p[p + 3], sD);
                uA = __builtin_elementwise_fma(hup[p],     w1p[p],     uA);
                uB = __builtin_elementwise_fma(hup[p + 1], w1p[p + 1], uB);
                uC = __builtin_elementwise_fma(hup[p + 2], w1p[p + 2], uC);
                uD = __builtin_elementwise_fma(hup[p + 3], w1p[p + 3], uD);
            }
            v2f sS = (sA + sB) + (sC + sD);
            v2f uS = (uA + uB) + (uC + uD);
            float acc0 = sS[0] + sS[1];
            float acc1 = uS[0] + uS[1];

            float iv, fv, gv, ov;
            half_bcast(acc0, iv, fv);
            half_bcast(acc1, gv, ov);

            c = sig2(fv) * c + sig2(iv) * tanh2(gv);
            h = sig2(ov) * tanh2(c * (2.0f * LOG2E));

            hsave[k] = h;
        }

        if (lane < 32) {
#pragma unroll
            for (int k = 0; k < KB; ++k)
                hp[(size_t)(t0 + k) * HID] = hsave[k];
        }

#pragma unroll
        for (int k = 0; k < KB; ++k) {
            xc0[k] = xn0[k];
            xc1[k] = xn1[k];
        }
    }
}

// ---------------------------------------------------------------------------
// Kernel 3: logits[pos][v] = h[pos] . w_out[v] + b_out[v]
// R18-proven skeleton (scalar h loads, packed FMAs, float2 store).
// Deltas: POS_PER_WAVE 16->8 (2x waves = 2x TLP for load-latency hiding) and
// full unroll of the position loop (compile-time positions -> compiler can
// software-pipeline the independent scalar h loads across positions).
// ---------------------------------------------------------------------------
#define POS_PER_WAVE 8
#define TOTAL_POS (BATCH * SEQ)

__global__ __launch_bounds__(256) void out_proj(
    const float* __restrict__ h,      // [B*T][32]
    const float* __restrict__ w_out,  // [128][32]
    const float* __restrict__ b_out,  // [128]
    float*       __restrict__ out)    // [B*T][128]
{
    const int gtid = blockIdx.x * blockDim.x + threadIdx.x;
    const int wave = gtid >> 6;
    const int lane = threadIdx.x & 63;
    const int v0   = 2 * lane;        // this lane's two vocab entries

    v2f wv0[HID / 2], wv1[HID / 2];
#pragma unroll
    for (int p = 0; p < HID / 2; ++p) {
        wv0[p][0] = w_out[v0 * HID + 2 * p];
        wv0[p][1] = w_out[v0 * HID + 2 * p + 1];
        wv1[p][0] = w_out[(v0 + 1) * HID + 2 * p];
        wv1[p][1] = w_out[(v0 + 1) * HID + 2 * p + 1];
    }
    const float bb0 = b_out[v0];
    const float bb1 = b_out[v0 + 1];

    const int pos0 = wave * POS_PER_WAVE;
#pragma unroll
    for (int p = 0; p < POS_PER_WAVE; ++p) {
        int pos = __builtin_amdgcn_readfirstlane(pos0 + p);
        const float* hp = h + (size_t)pos * HID;   // uniform -> scalar loads
        v2f lA = {bb0, 0.0f}, lB = {0.0f, 0.0f};   // vocab v0
        v2f mA = {bb1, 0.0f}, mB = {0.0f, 0.0f};   // vocab v0+1
#pragma unroll
        for (int j4 = 0; j4 < HID / 4; ++j4) {     // 8 uniform float4 loads
            float4 hv = *reinterpret_cast<const float4*>(hp + 4 * j4);
            v2f h01 = {hv.x, hv.y};
            v2f h23 = {hv.z, hv.w};
            lA = __builtin_elementwise_fma(h01, wv0[2 * j4],     lA);
            lB = __builtin_elementwise_fma(h23, wv0[2 * j4 + 1], lB);
            mA = __builtin_elementwise_fma(h01, wv1[2 * j4],     mA);
            mB = __builtin_elementwise_fma(h23, wv1[2 * j4 + 1], mB);
        }
        v2f lS = lA + lB;
        v2f mS = mA + mB;
        float2 r;
        r.x = lS[0] + lS[1];
        r.y = mS[0] + mS[1];
        *reinterpret_cast<float2*>(out + (size_t)pos * VOCAB + v0) = r;
    }
}

// ---------------------------------------------------------------------------
extern "C" void kernel_launch(void* const* d_in, const int* in_sizes, int n_in,
                              void* d_out, int out_size, void* d_ws, size_t ws_size,
                              hipStream_t stream) {
    const int*   tokens = (const int*)  d_in[0];
    const float* emb    = (const float*)d_in[1];
    const float* w_ih   = (const float*)d_in[2];
    const float* w_hh   = (const float*)d_in[3];
    const float* b_ih   = (const float*)d_in[4];
    const float* b_hh   = (const float*)d_in[5];
    const float* w_out  = (const float*)d_in[6];
    const float* b_out  = (const float*)d_in[7];
    float*       out    = (float*)d_out;

    float* proj = (float*)d_ws;
    float* hbuf = (float*)((char*)d_ws + VOCAB * G4 * sizeof(float));

    build_proj<<<(VOCAB * G4) / 256, 256, 0, stream>>>(emb, w_ih, b_ih, b_hh, proj);

    lstm_rec<<<BATCH, 64, 0, stream>>>(tokens, w_hh, proj, hbuf);

    const int waves = TOTAL_POS / POS_PER_WAVE;           // 32768
    out_proj<<<waves / 4, 256, 0, stream>>>(hbuf, w_out, b_out, out);
}

// Round 20
// 175.435 us; speedup vs baseline: 1.1631x; 1.1631x over previous
//
#include <hip/hip_runtime.h>

#define VOCAB 128
#define EMB   8
#define HID   32
#define BATCH 512
#define SEQ   512
#define G4    128   // 4*HID
#define KB    8     // recurrence steps per phase

#define LOG2E 1.4426950408889634f

typedef float v2f __attribute__((ext_vector_type(2)));

// ---------------------------------------------------------------------------
// Kernel 1: proj[v][r] = (dot(emb[v], w_ih[r]) + b_ih[r] + b_hh[r]) * rowscale
// rowscale folds exp->exp2: g-rows [64,96): 2*log2e ; others: log2e
// ---------------------------------------------------------------------------
__global__ void build_proj(const float* __restrict__ emb,
                           const float* __restrict__ w_ih,
                           const float* __restrict__ b_ih,
                           const float* __restrict__ b_hh,
                           float* __restrict__ proj) {
    int idx = blockIdx.x * blockDim.x + threadIdx.x;   // 0 .. 16383
    int v = idx >> 7;
    int r = idx & 127;
    float acc = b_ih[r] + b_hh[r];
#pragma unroll
    for (int e = 0; e < EMB; ++e)
        acc += emb[v * EMB + e] * w_ih[r * EMB + e];
    float sc = (r >= 64 && r < 96) ? (2.0f * LOG2E) : LOG2E;
    proj[v * G4 + r] = acc * sc;
}

// ---------------------------------------------------------------------------
// Fast gate nonlinearities (inputs pre-scaled by log2e / 2*log2e). Proven R10.
// ---------------------------------------------------------------------------
__device__ __forceinline__ float sig2(float x) {
    return __builtin_amdgcn_rcpf(1.0f + __builtin_amdgcn_exp2f(-x));
}
__device__ __forceinline__ float tanh2(float x2) {
    return 1.0f - 2.0f * __builtin_amdgcn_rcpf(__builtin_amdgcn_exp2f(x2) + 1.0f);
}

// ---------------------------------------------------------------------------
// Alias-proof half-broadcast (proven R10).
// ---------------------------------------------------------------------------
__device__ __forceinline__ void half_bcast(float acc, float& lo, float& hi) {
    asm("v_mov_b32 %0, %2\n\t"
        "v_mov_b32 %1, %2\n\t"
        "v_permlane32_swap_b32 %0, %1"
        : "=&v"(lo), "=&v"(hi)
        : "v"(acc));
}

// ---------------------------------------------------------------------------
// Kernel 2: LSTM recurrence — R15 VERBATIM (133-134 us, green).
// ---------------------------------------------------------------------------
__global__ __launch_bounds__(64)
__attribute__((amdgpu_waves_per_eu(1, 1)))
void lstm_rec(
    const int*   __restrict__ tokens,   // [B][T]
    const float* __restrict__ w_hh,     // [128][32]
    const float* __restrict__ proj,     // [128][128], pre-scaled
    float*       __restrict__ h_out)    // [B*T][32]
{
    const int b    = blockIdx.x;
    const int lane = threadIdx.x;      // 0..63

    __shared__ float sproj[VOCAB * G4];   // 64 KB

    {
        const float4* src = (const float4*)proj;
        float4*       dst = (float4*)sproj;
#pragma unroll 4
        for (int i = 0; i < (VOCAB * G4 / 4) / 64; ++i)
            dst[i * 64 + lane] = src[i * 64 + lane];
    }

    const float sc1 = (lane < 32) ? (2.0f * LOG2E) : LOG2E;
    v2f w0p[HID / 2], w1p[HID / 2];
#pragma unroll
    for (int p = 0; p < HID / 2; ++p) {
        w0p[p][0] = w_hh[lane * HID + 2 * p]     * LOG2E;
        w0p[p][1] = w_hh[lane * HID + 2 * p + 1] * LOG2E;
        w1p[p][0] = w_hh[(lane + 64) * HID + 2 * p]     * sc1;
        w1p[p][1] = w_hh[(lane + 64) * HID + 2 * p + 1] * sc1;
    }
#pragma unroll
    for (int p = 0; p < HID / 2; ++p) {
        asm volatile("" : "+v"(w0p[p]), "+v"(w1p[p]));
    }

    const int* tok = tokens + b * SEQ;
    int tv[KB];
    {
        int4 a = ((const int4*)tok)[lane * 2];
        int4 d = ((const int4*)tok)[lane * 2 + 1];
        tv[0] = a.x; tv[1] = a.y; tv[2] = a.z; tv[3] = a.w;
        tv[4] = d.x; tv[5] = d.y; tv[6] = d.z; tv[7] = d.w;
    }

    __syncthreads();

    float h = 0.0f, c = 0.0f;
    float* hp = h_out + (size_t)b * SEQ * HID + lane;
    float hsave[KB];

    float xc0[KB], xc1[KB];
#pragma unroll
    for (int k = 0; k < KB; ++k) {
        int tk = __builtin_amdgcn_readlane(tv[k], 0);
        xc0[k] = sproj[tk * G4 + lane];
        xc1[k] = sproj[tk * G4 + 64 + lane];
    }

    for (int t0 = 0; t0 < SEQ; t0 += KB) {
        const int nb = t0 + KB;
        const int ln = (nb < SEQ) ? (nb >> 3) : 0;
        float xn0[KB], xn1[KB];
#pragma unroll
        for (int k = 0; k < KB; ++k) {
            int tk = __builtin_amdgcn_readlane(tv[k], ln);
            xn0[k] = sproj[tk * G4 + lane];
            xn1[k] = sproj[tk * G4 + 64 + lane];
        }
        __builtin_amdgcn_sched_barrier(0);

#pragma unroll
        for (int k = 0; k < KB; ++k) {
            unsigned hb = __float_as_uint(h);
            v2f hup[HID / 2];
#pragma unroll
            for (int p = 0; p < HID / 2; ++p) {
                hup[p][0] = __uint_as_float(__builtin_amdgcn_readlane(hb, 2 * p));
                hup[p][1] = __uint_as_float(__builtin_amdgcn_readlane(hb, 2 * p + 1));
            }
            __builtin_amdgcn_sched_barrier(0);

            v2f sA = {xc0[k], 0.0f}, sB = {0.0f, 0.0f},
                sC = {0.0f, 0.0f},   sD = {0.0f, 0.0f};
            v2f uA = {xc1[k], 0.0f}, uB = {0.0f, 0.0f},
                uC = {0.0f, 0.0f},   uD = {0.0f, 0.0f};
#pragma unroll
            for (int p = 0; p < HID / 2; p += 4) {
                sA = __builtin_elementwise_fma(hup[p],     w0p[p],     sA);
                sB = __builtin_elementwise_fma(hup[p + 1], w0p[p + 1], sB);
                sC = __builtin_elementwise_fma(hup[p + 2], w0p[p + 2], sC);
                sD = __builtin_elementwise_fma(hup[p + 3], w0p[p + 3], sD);
                uA = __builtin_elementwise_fma(hup[p],     w1p[p],     uA);
                uB = __builtin_elementwise_fma(hup[p + 1], w1p[p + 1], uB);
                uC = __builtin_elementwise_fma(hup[p + 2], w1p[p + 2], uC);
                uD = __builtin_elementwise_fma(hup[p + 3], w1p[p + 3], uD);
            }
            v2f sS = (sA + sB) + (sC + sD);
            v2f uS = (uA + uB) + (uC + uD);
            float acc0 = sS[0] + sS[1];
            float acc1 = uS[0] + uS[1];

            float iv, fv, gv, ov;
            half_bcast(acc0, iv, fv);
            half_bcast(acc1, gv, ov);

            c = sig2(fv) * c + sig2(iv) * tanh2(gv);
            h = sig2(ov) * tanh2(c * (2.0f * LOG2E));

            hsave[k] = h;
        }

        if (lane < 32) {
#pragma unroll
            for (int k = 0; k < KB; ++k)
                hp[(size_t)(t0 + k) * HID] = hsave[k];
        }

#pragma unroll
        for (int k = 0; k < KB; ++k) {
            xc0[k] = xn0[k];
            xc1[k] = xn1[k];
        }
    }
}

// ---------------------------------------------------------------------------
// Kernel 3: logits[pos][v] = h[pos] . w_out[v] + b_out[v]
// R18-proven skeleton (scalar h loads via readfirstlane-uniform address,
// packed FMAs, one float2 store/position). SINGLE DELTA vs R18:
// POS_PER_WAVE 16 -> 32 (halves per-position weight-preload amortized cost;
// R19 proved the overhead scales with wave count, not TLP-limited).
// ---------------------------------------------------------------------------
#define POS_PER_WAVE 32
#define TOTAL_POS (BATCH * SEQ)

__global__ __launch_bounds__(256) void out_proj(
    const float* __restrict__ h,      // [B*T][32]
    const float* __restrict__ w_out,  // [128][32]
    const float* __restrict__ b_out,  // [128]
    float*       __restrict__ out)    // [B*T][128]
{
    const int gtid = blockIdx.x * blockDim.x + threadIdx.x;
    const int wave = gtid >> 6;
    const int lane = threadIdx.x & 63;
    const int v0   = 2 * lane;        // this lane's two vocab entries

    v2f wv0[HID / 2], wv1[HID / 2];
#pragma unroll
    for (int p = 0; p < HID / 2; ++p) {
        wv0[p][0] = w_out[v0 * HID + 2 * p];
        wv0[p][1] = w_out[v0 * HID + 2 * p + 1];
        wv1[p][0] = w_out[(v0 + 1) * HID + 2 * p];
        wv1[p][1] = w_out[(v0 + 1) * HID + 2 * p + 1];
    }
    const float bb0 = b_out[v0];
    const float bb1 = b_out[v0 + 1];

    int pos0 = wave * POS_PER_WAVE;
    for (int p = 0; p < POS_PER_WAVE; ++p) {
        int pos = __builtin_amdgcn_readfirstlane(pos0 + p);
        const float* hp = h + (size_t)pos * HID;   // uniform -> scalar loads
        v2f lA = {bb0, 0.0f}, lB = {0.0f, 0.0f};   // vocab v0
        v2f mA = {bb1, 0.0f}, mB = {0.0f, 0.0f};   // vocab v0+1
#pragma unroll
        for (int j4 = 0; j4 < HID / 4; ++j4) {     // 8 uniform float4 loads
            float4 hv = *reinterpret_cast<const float4*>(hp + 4 * j4);
            v2f h01 = {hv.x, hv.y};
            v2f h23 = {hv.z, hv.w};
            lA = __builtin_elementwise_fma(h01, wv0[2 * j4],     lA);
            lB = __builtin_elementwise_fma(h23, wv0[2 * j4 + 1], lB);
            mA = __builtin_elementwise_fma(h01, wv1[2 * j4],     mA);
            mB = __builtin_elementwise_fma(h23, wv1[2 * j4 + 1], mB);
        }
        v2f lS = lA + lB;
        v2f mS = mA + mB;
        float2 r;
        r.x = lS[0] + lS[1];
        r.y = mS[0] + mS[1];
        *reinterpret_cast<float2*>(out + (size_t)pos * VOCAB + v0) = r;
    }
}

// ---------------------------------------------------------------------------
extern "C" void kernel_launch(void* const* d_in, const int* in_sizes, int n_in,
                              void* d_out, int out_size, void* d_ws, size_t ws_size,
                              hipStream_t stream) {
    const int*   tokens = (const int*)  d_in[0];
    const float* emb    = (const float*)d_in[1];
    const float* w_ih   = (const float*)d_in[2];
    const float* w_hh   = (const float*)d_in[3];
    const float* b_ih   = (const float*)d_in[4];
    const float* b_hh   = (const float*)d_in[5];
    const float* w_out  = (const float*)d_in[6];
    const float* b_out  = (const float*)d_in[7];
    float*       out    = (float*)d_out;

    float* proj = (float*)d_ws;
    float* hbuf = (float*)((char*)d_ws + VOCAB * G4 * sizeof(float));

    build_proj<<<(VOCAB * G4) / 256, 256, 0, stream>>>(emb, w_ih, b_ih, b_hh, proj);

    lstm_rec<<<BATCH, 64, 0, stream>>>(tokens, w_hh, proj, hbuf);

    const int waves = TOTAL_POS / POS_PER_WAVE;           // 8192
    out_proj<<<waves / 4, 256, 0, stream>>>(hbuf, w_out, b_out, out);
}